// Round 1
// baseline (919.651 us; speedup 1.0000x reference)
//
#include <hip/hip_runtime.h>
#include <math.h>

#define N_PTS (128*128*128)          // 2,097,152
#define T_HASH 4194304
#define T_MASK (T_HASH - 1)

// ---------------------------------------------------------------------------
// Pass 1: global sum / sum-of-squares over gf[0:3] (3*N elements).
// Per-thread float partials -> wave shuffle reduce -> block reduce -> double
// device-scope atomics into ws (zeroed each launch via hipMemsetAsync).
// ---------------------------------------------------------------------------
__global__ void reduce_kernel(const int* __restrict__ coords,
                              const float* __restrict__ table,
                              double* __restrict__ acc) {
    float s = 0.f, ss = 0.f;
    const int stride = gridDim.x * blockDim.x;
    for (int i = blockIdx.x * blockDim.x + threadIdx.x; i < N_PTS; i += stride) {
        unsigned x = (unsigned)coords[i * 3 + 0];
        unsigned y = (unsigned)coords[i * 3 + 1];
        unsigned z = (unsigned)coords[i * 3 + 2];
        unsigned idx = (x ^ (y * 2654435761u) ^ (z * 805459861u)) & T_MASK;
        float g0 = table[idx];
        float g1 = table[T_HASH + idx];
        float g2 = table[2 * T_HASH + idx];
        s  += g0 + g1 + g2;
        ss += g0 * g0 + g1 * g1 + g2 * g2;
    }
    // wave-64 butterfly-free down-reduce
    #pragma unroll
    for (int off = 32; off > 0; off >>= 1) {
        s  += __shfl_down(s, off, 64);
        ss += __shfl_down(ss, off, 64);
    }
    __shared__ float sh_s[4], sh_ss[4];
    const int lane = threadIdx.x & 63;
    const int wid  = threadIdx.x >> 6;
    if (lane == 0) { sh_s[wid] = s; sh_ss[wid] = ss; }
    __syncthreads();
    if (threadIdx.x == 0) {
        float ts = 0.f, tss = 0.f;
        for (int w = 0; w < 4; ++w) { ts += sh_s[w]; tss += sh_ss[w]; }
        atomicAdd(&acc[0], (double)ts);
        atomicAdd(&acc[1], (double)tss);
    }
}

// ---------------------------------------------------------------------------
// Pass 2: gather all 14 features, compute means / covariances / harmonics /
// opacities. Output layout (flat, concatenated in return order):
//   [0,          3N)  means        (N,3)
//   [3N,        12N)  covariances  (N,3,3)
//   [12N,       15N)  harmonics    (N,3,1)
//   [15N,       16N)  opacities    (N,)
// ---------------------------------------------------------------------------
__global__ void main_kernel(const int* __restrict__ coords,
                            const float* __restrict__ table,
                            const float* __restrict__ cam,
                            const float* __restrict__ far_p,
                            const int* __restrict__ vs_p,
                            const double* __restrict__ acc,
                            float* __restrict__ out) {
    const int i = blockIdx.x * blockDim.x + threadIdx.x;
    if (i >= N_PTS) return;

    const float far_s = far_p[0];
    const float vs    = (float)vs_p[0];

    // global mean / std (ddof=1) from pass-1 accumulators
    const double n     = 3.0 * (double)N_PTS;
    const double sum   = acc[0];
    const double sumsq = acc[1];
    const double mean_d = sum / n;
    const double var_d  = (sumsq - sum * sum / n) / (n - 1.0);
    const float mean    = (float)mean_d;
    const float inv_std = (float)(1.0 / sqrt(var_d));

    const int cx = coords[i * 3 + 0];
    const int cy = coords[i * 3 + 1];
    const int cz = coords[i * 3 + 2];
    const unsigned idx = ((unsigned)cx ^ ((unsigned)cy * 2654435761u)
                                       ^ ((unsigned)cz * 805459861u)) & T_MASK;

    float g[14];
    #pragma unroll
    for (int j = 0; j < 14; ++j)
        g[j] = table[(size_t)j * T_HASH + idx];

    const float two_far_over_vs = 2.f * far_s / vs;

    // voxel_center + normalized displacement -> means
    const float dm_scale = two_far_over_vs / 6.f;
    float vc[3];
    const float c_f[3] = { (float)cx, (float)cy, (float)cz };
    #pragma unroll
    for (int k = 0; k < 3; ++k)
        vc[k] = c_f[k] / vs * 2.f * far_s - far_s + cam[k] + far_s / vs;

    #pragma unroll
    for (int k = 0; k < 3; ++k)
        out[(size_t)i * 3 + k] = (g[k] - mean) * inv_std * dm_scale + vc[k];

    // quaternion -> rotation matrix
    float qr = g[3], qx = g[4], qy = g[5], qz = g[6];
    const float qinv = 1.f / sqrtf(qr * qr + qx * qx + qy * qy + qz * qz);
    qr *= qinv; qx *= qinv; qy *= qinv; qz *= qinv;

    float R[3][3];
    R[0][0] = 1.f - 2.f * (qy * qy + qz * qz);
    R[0][1] = 2.f * (qx * qy - qr * qz);
    R[0][2] = 2.f * (qx * qz + qr * qy);
    R[1][0] = 2.f * (qx * qy + qr * qz);
    R[1][1] = 1.f - 2.f * (qx * qx + qz * qz);
    R[1][2] = 2.f * (qy * qz - qr * qx);
    R[2][0] = 2.f * (qx * qz - qr * qy);
    R[2][1] = 2.f * (qy * qz + qr * qx);
    R[2][2] = 1.f - 2.f * (qx * qx + qy * qy);

    // scales = sigmoid(g[7:10]) * 2*far/vs
    float sc[3];
    #pragma unroll
    for (int k = 0; k < 3; ++k)
        sc[k] = two_far_over_vs / (1.f + expf(-g[7 + k]));

    // L = R * diag(scales); cov = L L^T
    float* covp = out + (size_t)3 * N_PTS + (size_t)i * 9;
    #pragma unroll
    for (int r = 0; r < 3; ++r) {
        #pragma unroll
        for (int c = 0; c < 3; ++c) {
            float acc_rc = 0.f;
            #pragma unroll
            for (int j = 0; j < 3; ++j)
                acc_rc += (R[r][j] * sc[j]) * (R[c][j] * sc[j]);
            covp[r * 3 + c] = acc_rc;
        }
    }

    // harmonics
    float* harp = out + (size_t)12 * N_PTS + (size_t)i * 3;
    #pragma unroll
    for (int k = 0; k < 3; ++k)
        harp[k] = g[10 + k];

    // opacity = sigmoid(g[13] - 4)
    out[(size_t)15 * N_PTS + i] = 1.f / (1.f + expf(-(g[13] - 4.f)));
}

extern "C" void kernel_launch(void* const* d_in, const int* in_sizes, int n_in,
                              void* d_out, int out_size, void* d_ws, size_t ws_size,
                              hipStream_t stream) {
    const int*   coords = (const int*)d_in[0];
    const float* table  = (const float*)d_in[1];
    const float* cam    = (const float*)d_in[2];
    const float* far_p  = (const float*)d_in[3];
    const int*   vs_p   = (const int*)d_in[4];
    float*       out    = (float*)d_out;
    double*      acc    = (double*)d_ws;

    // ws is re-poisoned (0xAA) before every timed launch — zero the accumulators.
    hipMemsetAsync(d_ws, 0, 2 * sizeof(double), stream);

    reduce_kernel<<<2048, 256, 0, stream>>>(coords, table, acc);

    const int threads = 256;
    const int blocks  = (N_PTS + threads - 1) / threads;
    main_kernel<<<blocks, threads, 0, stream>>>(coords, table, cam, far_p, vs_p,
                                                acc, out);
}

// Round 2
// 543.584 us; speedup vs baseline: 1.6918x; 1.6918x over previous
//
#include <hip/hip_runtime.h>
#include <math.h>

#define N_PTS (128*128*128)          // 2,097,152
#define T_HASH 4194304
#define T_MASK (T_HASH - 1)
#define ENTRY_STRIDE 16              // floats per transposed entry (64 B aligned)

__device__ __forceinline__ unsigned hash_idx(int x, int y, int z) {
    return ((unsigned)x ^ ((unsigned)y * 2654435761u)
                        ^ ((unsigned)z * 805459861u)) & T_MASK;
}

// ---------------------------------------------------------------------------
// Kernel 1: transpose (14, T_HASH) -> (T_HASH, 16) padded, all coalesced.
// ---------------------------------------------------------------------------
__global__ void transpose_kernel(const float* __restrict__ table,
                                 float* __restrict__ tt) {
    __shared__ float sh[256 * 17];   // +1 pad breaks stride-16 bank conflicts
    const int t  = threadIdx.x;
    const int i0 = blockIdx.x * 256;

    #pragma unroll
    for (int j = 0; j < 14; ++j)
        sh[t * 17 + j] = table[(size_t)j * T_HASH + i0 + t];   // coalesced read
    sh[t * 17 + 14] = 0.f;
    sh[t * 17 + 15] = 0.f;
    __syncthreads();

    // write 256 entries * 64 B = 16 KB contiguous, coalesced float4 stores
    float4* dst = (float4*)(tt + (size_t)i0 * ENTRY_STRIDE);
    #pragma unroll
    for (int k = 0; k < 4; ++k) {
        const int f = t + k * 256;         // float4 slot in [0,1024)
        const int p = f >> 2;              // entry within block
        const int c = f & 3;               // float4 within entry
        const float* s = &sh[p * 17 + c * 4];
        dst[f] = make_float4(s[0], s[1], s[2], s[3]);
    }
}

// ---------------------------------------------------------------------------
// Kernel 2: sum / sumsq over gathered rows 0:3 -- one float4 gather per point.
// ---------------------------------------------------------------------------
__global__ void reduce_kernel_t(const int* __restrict__ coords,
                                const float* __restrict__ tt,
                                double* __restrict__ acc) {
    float s = 0.f, ss = 0.f;
    const int stride = gridDim.x * blockDim.x;
    for (int i = blockIdx.x * blockDim.x + threadIdx.x; i < N_PTS; i += stride) {
        const unsigned idx = hash_idx(coords[i*3], coords[i*3+1], coords[i*3+2]);
        const float4 f = *(const float4*)(tt + (size_t)idx * ENTRY_STRIDE);
        s  += f.x + f.y + f.z;
        ss += f.x * f.x + f.y * f.y + f.z * f.z;
    }
    #pragma unroll
    for (int off = 32; off > 0; off >>= 1) {
        s  += __shfl_down(s, off, 64);
        ss += __shfl_down(ss, off, 64);
    }
    __shared__ float sh_s[4], sh_ss[4];
    const int lane = threadIdx.x & 63;
    const int wid  = threadIdx.x >> 6;
    if (lane == 0) { sh_s[wid] = s; sh_ss[wid] = ss; }
    __syncthreads();
    if (threadIdx.x == 0) {
        float ts = 0.f, tss = 0.f;
        for (int w = 0; w < 4; ++w) { ts += sh_s[w]; tss += sh_ss[w]; }
        atomicAdd(&acc[0], (double)ts);
        atomicAdd(&acc[1], (double)tss);
    }
}

// Fallback reduce from original layout (used when ws too small for transpose)
__global__ void reduce_kernel_o(const int* __restrict__ coords,
                                const float* __restrict__ table,
                                double* __restrict__ acc) {
    float s = 0.f, ss = 0.f;
    const int stride = gridDim.x * blockDim.x;
    for (int i = blockIdx.x * blockDim.x + threadIdx.x; i < N_PTS; i += stride) {
        const unsigned idx = hash_idx(coords[i*3], coords[i*3+1], coords[i*3+2]);
        float g0 = table[idx];
        float g1 = table[T_HASH + idx];
        float g2 = table[2 * T_HASH + idx];
        s  += g0 + g1 + g2;
        ss += g0 * g0 + g1 * g1 + g2 * g2;
    }
    #pragma unroll
    for (int off = 32; off > 0; off >>= 1) {
        s  += __shfl_down(s, off, 64);
        ss += __shfl_down(ss, off, 64);
    }
    __shared__ float sh_s[4], sh_ss[4];
    const int lane = threadIdx.x & 63;
    const int wid  = threadIdx.x >> 6;
    if (lane == 0) { sh_s[wid] = s; sh_ss[wid] = ss; }
    __syncthreads();
    if (threadIdx.x == 0) {
        float ts = 0.f, tss = 0.f;
        for (int w = 0; w < 4; ++w) { ts += sh_s[w]; tss += sh_ss[w]; }
        atomicAdd(&acc[0], (double)ts);
        atomicAdd(&acc[1], (double)tss);
    }
}

// ---------------------------------------------------------------------------
// Main compute: TRANSPOSED selects gather source.
// Output layout: [0,3N) means | [3N,12N) cov | [12N,15N) harm | [15N,16N) opac
// ---------------------------------------------------------------------------
template <bool TRANSPOSED>
__global__ void main_kernel(const int* __restrict__ coords,
                            const float* __restrict__ tab,   // tt or table
                            const float* __restrict__ cam,
                            const float* __restrict__ far_p,
                            const int* __restrict__ vs_p,
                            const double* __restrict__ acc,
                            float* __restrict__ out) {
    const int i = blockIdx.x * blockDim.x + threadIdx.x;
    if (i >= N_PTS) return;

    const float far_s = far_p[0];
    const float vs    = (float)vs_p[0];

    const double n      = 3.0 * (double)N_PTS;
    const double sum    = acc[0];
    const double sumsq  = acc[1];
    const double mean_d = sum / n;
    const double var_d  = (sumsq - sum * sum / n) / (n - 1.0);
    const float mean    = (float)mean_d;
    const float inv_std = (float)(1.0 / sqrt(var_d));

    const int cx = coords[i * 3 + 0];
    const int cy = coords[i * 3 + 1];
    const int cz = coords[i * 3 + 2];
    const unsigned idx = hash_idx(cx, cy, cz);

    float g[16];
    if (TRANSPOSED) {
        const float4* e = (const float4*)(tab + (size_t)idx * ENTRY_STRIDE);
        float4 f0 = e[0], f1 = e[1], f2 = e[2], f3 = e[3];
        g[0]=f0.x; g[1]=f0.y; g[2]=f0.z; g[3]=f0.w;
        g[4]=f1.x; g[5]=f1.y; g[6]=f1.z; g[7]=f1.w;
        g[8]=f2.x; g[9]=f2.y; g[10]=f2.z; g[11]=f2.w;
        g[12]=f3.x; g[13]=f3.y;
    } else {
        #pragma unroll
        for (int j = 0; j < 14; ++j)
            g[j] = tab[(size_t)j * T_HASH + idx];
    }

    const float two_far_over_vs = 2.f * far_s / vs;
    const float dm_scale = two_far_over_vs / 6.f;
    const float c_f[3] = { (float)cx, (float)cy, (float)cz };
    #pragma unroll
    for (int k = 0; k < 3; ++k) {
        const float vc = c_f[k] / vs * 2.f * far_s - far_s + cam[k] + far_s / vs;
        out[(size_t)i * 3 + k] = (g[k] - mean) * inv_std * dm_scale + vc;
    }

    float qr = g[3], qx = g[4], qy = g[5], qz = g[6];
    const float qinv = 1.f / sqrtf(qr * qr + qx * qx + qy * qy + qz * qz);
    qr *= qinv; qx *= qinv; qy *= qinv; qz *= qinv;

    float R[3][3];
    R[0][0] = 1.f - 2.f * (qy * qy + qz * qz);
    R[0][1] = 2.f * (qx * qy - qr * qz);
    R[0][2] = 2.f * (qx * qz + qr * qy);
    R[1][0] = 2.f * (qx * qy + qr * qz);
    R[1][1] = 1.f - 2.f * (qx * qx + qz * qz);
    R[1][2] = 2.f * (qy * qz - qr * qx);
    R[2][0] = 2.f * (qx * qz - qr * qy);
    R[2][1] = 2.f * (qy * qz + qr * qx);
    R[2][2] = 1.f - 2.f * (qx * qx + qy * qy);

    float sc[3];
    #pragma unroll
    for (int k = 0; k < 3; ++k)
        sc[k] = two_far_over_vs / (1.f + expf(-g[7 + k]));

    float* covp = out + (size_t)3 * N_PTS + (size_t)i * 9;
    #pragma unroll
    for (int r = 0; r < 3; ++r) {
        #pragma unroll
        for (int c = 0; c < 3; ++c) {
            float a = 0.f;
            #pragma unroll
            for (int j = 0; j < 3; ++j)
                a += (R[r][j] * sc[j]) * (R[c][j] * sc[j]);
            covp[r * 3 + c] = a;
        }
    }

    float* harp = out + (size_t)12 * N_PTS + (size_t)i * 3;
    #pragma unroll
    for (int k = 0; k < 3; ++k)
        harp[k] = g[10 + k];

    out[(size_t)15 * N_PTS + i] = 1.f / (1.f + expf(-(g[13] - 4.f)));
}

extern "C" void kernel_launch(void* const* d_in, const int* in_sizes, int n_in,
                              void* d_out, int out_size, void* d_ws, size_t ws_size,
                              hipStream_t stream) {
    const int*   coords = (const int*)d_in[0];
    const float* table  = (const float*)d_in[1];
    const float* cam    = (const float*)d_in[2];
    const float* far_p  = (const float*)d_in[3];
    const int*   vs_p   = (const int*)d_in[4];
    float*       out    = (float*)d_out;

    double* acc = (double*)d_ws;
    float*  tt  = (float*)((char*)d_ws + 256);

    const size_t need = 256 + (size_t)T_HASH * ENTRY_STRIDE * sizeof(float);

    hipMemsetAsync(d_ws, 0, 2 * sizeof(double), stream);

    const int threads = 256;
    const int blocks  = (N_PTS + threads - 1) / threads;

    if (ws_size >= need) {
        transpose_kernel<<<T_HASH / 256, 256, 0, stream>>>(table, tt);
        reduce_kernel_t<<<2048, 256, 0, stream>>>(coords, tt, acc);
        main_kernel<true><<<blocks, threads, 0, stream>>>(coords, tt, cam, far_p,
                                                          vs_p, acc, out);
    } else {
        reduce_kernel_o<<<2048, 256, 0, stream>>>(coords, table, acc);
        main_kernel<false><<<blocks, threads, 0, stream>>>(coords, table, cam,
                                                           far_p, vs_p, acc, out);
    }
}